// Round 9
// baseline (212.275 us; speedup 1.0000x reference)
//
#include <hip/hip_runtime.h>
#include <math.h>

#define NCLS 10
#define CHUNK 2048
#define PDIM 64
#define LDX2 40   // padded row length (shorts) per feature in per-wave staging
#define LDE 68    // padded leading dim for 64x64 LDS matrices in logdet

typedef short bf16x8 __attribute__((ext_vector_type(8)));
typedef float f32x4 __attribute__((ext_vector_type(4)));

// round-to-nearest-even fp32 -> bf16 bits
__device__ __forceinline__ unsigned short bf16rn(float x) {
    unsigned u = __float_as_uint(x);
    return (unsigned short)((u + 0x7FFFu + ((u >> 16) & 1u)) >> 16);
}
__device__ __forceinline__ float bf16f(unsigned short h) {
    return __uint_as_float(((unsigned)h) << 16);
}

// tile index for (fi,fj), fi<=fj, in 0..9 (compile-time under full unroll)
#define TIDX(fi, fj) ((fi) * 4 + (fj) - ((fi) * ((fi) + 1)) / 2)

// ---------------------------------------------------------------------------
// ws layout:
//   [0, 180224)          float gram[11][64*64]  (0..9 class, 10 = total; upper tri)
//   [180224, 180264)     int   counts[10]
//   [180264, 180268)     unsigned done-counter
//   [180352, 180440)     double contrib[11]
// memset zeroes [0, 180268) each call.
// ---------------------------------------------------------------------------

// Kernel 1: per-(chunk, class) Gram accumulation via MFMA (bf16 hi/lo split),
// BARRIER-FREE main loop. Each wave owns a private LDS staging slice and a
// full symmetry-reduced 64x64 accumulator (10 upper 16x16 tiles, 40 AGPRs),
// and processes its own 32-row batches (b = w, w+4, ...). In-wave
// ds_write->ds_read ordering is guaranteed by the per-wave in-order DS pipe,
// so no __syncthreads between gather and flush; the compiler is free to
// overlap batch t+1 global loads with batch t MFMAs. Cross-wave reduction
// via LDS atomics into s_gram overlaid on the staging buffer.
__global__ __launch_bounds__(256) void mcr_gram(
    const float4* __restrict__ embed4,
    const int* __restrict__ targets,
    float* __restrict__ gram,
    int* __restrict__ counts,
    int m)
{
    __shared__ unsigned short s_list[CHUNK];                    // 4 KB
    __shared__ int s_cnt;
    __shared__ alignas(16) unsigned short s_stage[4][2][PDIM * LDX2];  // 40960 B

    const int tid = threadIdx.x;
    const int cls = blockIdx.y;
    const int base = blockIdx.x * CHUNK;
    const int lane = tid & 63;
    const int w = tid >> 6;

    if (tid == 0) s_cnt = 0;
    __syncthreads();

    // ---- Phase A: ballot-compacted gather ----
    const int lim = (m - base < CHUNK) ? (m - base) : CHUNK;
    for (int i = tid; i < lim; i += 256) {
        const bool match = (targets[base + i] == cls);
        const unsigned long long mk = __ballot(match);
        const int cnt = __popcll(mk);
        int wbase = 0;
        if (lane == 0 && cnt) wbase = atomicAdd(&s_cnt, cnt);
        wbase = __shfl(wbase, 0);
        if (match) {
            const int pre = __popcll(mk & ((1ull << lane) - 1ull));
            s_list[wbase + pre] = (unsigned short)i;
        }
    }
    __syncthreads();
    const int n = s_cnt;
    if (n == 0) return;
    if (tid == 0) atomicAdd(&counts[cls], n);

    // ---- Phase B: wave-independent MFMA accumulation ----
    const int rg = lane & 3;          // 8-row group within 32-row batch
    const int q  = lane >> 2;         // float4 feat-quad 0..15
    const int t16 = lane & 15;        // frag lane decomposition (R6-verified)
    const int s4  = lane >> 4;
    unsigned short* Xh = &s_stage[w][0][0];
    unsigned short* Xl = &s_stage[w][1][0];
    const float4 z4 = make_float4(0.f, 0.f, 0.f, 0.f);

    f32x4 acc[10];
#pragma unroll
    for (int i = 0; i < 10; ++i) acc[i] = (f32x4){0.f, 0.f, 0.f, 0.f};

    const int nb = (n + 31) >> 5;
    for (int b = w; b < nb; b += 4) {
        // load 8 rows x 4 feats (one float4 per row), zero-padded past n
        float4 v[8];
#pragma unroll
        for (int i = 0; i < 8; ++i) {
            const int idx = b * 32 + 8 * rg + i;
            if (idx < n)
                v[i] = embed4[(size_t)(base + (int)s_list[idx]) * 16 + q];
            else
                v[i] = z4;
        }
        // convert to bf16 hi/lo, pack 8 rows per feature, one b128 write each
#pragma unroll
        for (int j = 0; j < 4; ++j) {
            bf16x8 hv, lv;
#pragma unroll
            for (int i = 0; i < 8; ++i) {
                const float x = (j == 0) ? v[i].x : (j == 1) ? v[i].y
                              : (j == 2) ? v[i].z : v[i].w;
                const unsigned short h = bf16rn(x);
                hv[i] = (short)h;
                lv[i] = (short)bf16rn(x - bf16f(h));
            }
            const int f = q * 4 + j;
            *(bf16x8*)&Xh[f * LDX2 + 8 * rg] = hv;
            *(bf16x8*)&Xl[f * LDX2 + 8 * rg] = lv;
        }
        // read fragments (per-wave in-order DS: writes above are visible)
        bf16x8 fh[4], fl[4];
#pragma unroll
        for (int fb = 0; fb < 4; ++fb) {
            fh[fb] = *(const bf16x8*)&Xh[(fb * 16 + t16) * LDX2 + 8 * s4];
            fl[fb] = *(const bf16x8*)&Xl[(fb * 16 + t16) * LDX2 + 8 * s4];
        }
        // 10 upper tiles x 3 hi/lo combos = 30 MFMAs per 32 rows
#pragma unroll
        for (int fi = 0; fi < 4; ++fi)
#pragma unroll
            for (int fj = fi; fj < 4; ++fj) {
                const int t = TIDX(fi, fj);
                acc[t] = __builtin_amdgcn_mfma_f32_16x16x32_bf16(fh[fi], fh[fj], acc[t], 0, 0, 0);
                acc[t] = __builtin_amdgcn_mfma_f32_16x16x32_bf16(fh[fi], fl[fj], acc[t], 0, 0, 0);
                acc[t] = __builtin_amdgcn_mfma_f32_16x16x32_bf16(fl[fi], fh[fj], acc[t], 0, 0, 0);
            }
    }

    // ---- cross-wave reduce: overlay s_gram on the (now dead) staging ----
    __syncthreads();   // all waves done with s_stage
    float* s_gram = (float*)&s_stage[0][0][0];   // 16 KB < 40 KB
#pragma unroll
    for (int i = 0; i < 16; ++i) s_gram[tid + 256 * i] = 0.0f;
    __syncthreads();
#pragma unroll
    for (int fi = 0; fi < 4; ++fi)
#pragma unroll
        for (int fj = fi; fj < 4; ++fj) {
            const int t = TIDX(fi, fj);
            const int a0 = fi * 16 + s4 * 4;
            const int bc = fj * 16 + t16;
#pragma unroll
            for (int j = 0; j < 4; ++j)
                atomicAdd(&s_gram[(a0 + j) * PDIM + bc], acc[t][j]);
        }
    __syncthreads();

    // ---- global flush (upper triangle; class slot + total slot) ----
    float* gk = gram + cls * (PDIM * PDIM);
    float* gt = gram + NCLS * (PDIM * PDIM);
#pragma unroll
    for (int k = 0; k < 16; ++k) {
        const int e = tid + 256 * k;
        const int a = e >> 6, bc = e & 63;
        if (a <= bc) {
            const float val = s_gram[e];
            atomicAdd(&gk[e], val);
            atomicAdd(&gt[e], val);
        }
    }
}

__device__ __forceinline__ float gU(const float* __restrict__ gram, int k, int a, int b) {
    const int lo = a < b ? a : b;
    const int hi = a < b ? b : a;
    return gram[k * (PDIM * PDIM) + lo * PDIM + hi];
}

// Kernel 2 (fused): one block per matrix (k=0..9 class Grams, k=10 total).
// M = I + c*G, s = tr(M)/64, E = M/s - I (tr E == 0, spectral radius ~0.1).
// logdet(M) = 64*log(s) - tr(E^2)/2 + tr(E^3)/3 - ... - tr(E^8)/8.
// Last finishing block sums the 11 contribs and writes the output scalar.
__global__ __launch_bounds__(256) void mcr_logdet(
    const float* __restrict__ gram,
    const int* __restrict__ counts,
    double* __restrict__ contrib,
    unsigned* __restrict__ ctr,
    float* __restrict__ out,
    int m)
{
    __shared__ float E[PDIM * LDE];
    __shared__ float F[PDIM * LDE];
    __shared__ float H[PDIM * LDE];
    __shared__ float G3[PDIM * LDE];
    __shared__ double s_red[4][7];
    __shared__ double s_alpha, s_beta, s_logs, s_w;

    const int tid = threadIdx.x;
    const int k = blockIdx.x;           // 0..9 class, 10 = total
    const bool tot = (k == NCLS);

    // scalar prep: wave 0 reduces the diagonal in parallel
    if (tid < PDIM) {
        double d = (double)gU(gram, k, tid, tid);
#pragma unroll
        for (int off = 32; off > 0; off >>= 1) d += __shfl_down(d, off);
        if (tid == 0) {
            const double trG = d;
            const double denom = tot ? (double)m : ((double)counts[k] + 1e-8);
            const double c = (double)PDIM / (denom * 0.01);
            const double s = 1.0 + c * trG / (double)PDIM;
            s_alpha = c / s;
            s_beta = 1.0 / s - 1.0;
            s_logs = (double)PDIM * log(s);
            s_w = tot ? -0.5 : 0.5 * denom / (double)m;   // GAM1=GAM2=1
        }
    }
    __syncthreads();

    const double alpha = s_alpha;
    const double beta = s_beta;
    const int ta = (tid >> 4) << 2;
    const int tb = (tid & 15) << 2;

    // build E
#pragma unroll
    for (int i = 0; i < 4; ++i) {
        const int a = ta + i;
#pragma unroll
        for (int j = 0; j < 4; ++j) {
            const int b = tb + j;
            double v = alpha * (double)gU(gram, k, a, b);
            if (a == b) v += beta;
            E[a * LDE + b] = (float)v;
        }
    }
    __syncthreads();

    // F = E * E   (E symmetric -> row-major float4 reads)
    {
        float f[4][4];
#pragma unroll
        for (int i = 0; i < 4; ++i)
#pragma unroll
            for (int j = 0; j < 4; ++j) f[i][j] = 0.0f;
#pragma unroll 4
        for (int t = 0; t < PDIM; ++t) {
            const float4 ea4 = *reinterpret_cast<const float4*>(&E[t * LDE + ta]);
            const float4 eb4 = *reinterpret_cast<const float4*>(&E[t * LDE + tb]);
            const float ea[4] = {ea4.x, ea4.y, ea4.z, ea4.w};
            const float eb[4] = {eb4.x, eb4.y, eb4.z, eb4.w};
#pragma unroll
            for (int i = 0; i < 4; ++i)
#pragma unroll
                for (int j = 0; j < 4; ++j) f[i][j] = fmaf(ea[i], eb[j], f[i][j]);
        }
#pragma unroll
        for (int i = 0; i < 4; ++i)
            *reinterpret_cast<float4*>(&F[(ta + i) * LDE + tb]) =
                make_float4(f[i][0], f[i][1], f[i][2], f[i][3]);
    }
    __syncthreads();

    // H = F * F ; G3 = F * E   (one fused pass)
    {
        float h[4][4], g3[4][4];
#pragma unroll
        for (int i = 0; i < 4; ++i)
#pragma unroll
            for (int j = 0; j < 4; ++j) { h[i][j] = 0.0f; g3[i][j] = 0.0f; }
#pragma unroll 4
        for (int t = 0; t < PDIM; ++t) {
            const float4 fa4 = *reinterpret_cast<const float4*>(&F[t * LDE + ta]);
            const float4 fb4 = *reinterpret_cast<const float4*>(&F[t * LDE + tb]);
            const float4 eb4 = *reinterpret_cast<const float4*>(&E[t * LDE + tb]);
            const float fa[4] = {fa4.x, fa4.y, fa4.z, fa4.w};
            const float fb[4] = {fb4.x, fb4.y, fb4.z, fb4.w};
            const float eb[4] = {eb4.x, eb4.y, eb4.z, eb4.w};
#pragma unroll
            for (int i = 0; i < 4; ++i)
#pragma unroll
                for (int j = 0; j < 4; ++j) {
                    h[i][j] = fmaf(fa[i], fb[j], h[i][j]);
                    g3[i][j] = fmaf(fa[i], eb[j], g3[i][j]);
                }
        }
#pragma unroll
        for (int i = 0; i < 4; ++i) {
            *reinterpret_cast<float4*>(&H[(ta + i) * LDE + tb]) =
                make_float4(h[i][0], h[i][1], h[i][2], h[i][3]);
            *reinterpret_cast<float4*>(&G3[(ta + i) * LDE + tb]) =
                make_float4(g3[i][0], g3[i][1], g3[i][2], g3[i][3]);
        }
    }
    __syncthreads();

    // traces via elementwise sums (all matrices symmetric)
    double t2 = 0, t3 = 0, t4 = 0, t5 = 0, t6 = 0, t7 = 0, t8 = 0;
#pragma unroll
    for (int i = 0; i < 4; ++i)
#pragma unroll
        for (int j = 0; j < 4; ++j) {
            const int idx = (ta + i) * LDE + tb + j;
            const double e = (double)E[idx];
            const double f = (double)F[idx];
            const double h = (double)H[idx];
            const double g = (double)G3[idx];
            t2 += e * e; t3 += f * e; t4 += f * f;
            t5 += h * e; t6 += h * f; t7 += h * g; t8 += h * h;
        }
#pragma unroll
    for (int off = 32; off > 0; off >>= 1) {
        t2 += __shfl_down(t2, off);
        t3 += __shfl_down(t3, off);
        t4 += __shfl_down(t4, off);
        t5 += __shfl_down(t5, off);
        t6 += __shfl_down(t6, off);
        t7 += __shfl_down(t7, off);
        t8 += __shfl_down(t8, off);
    }
    const int lane = tid & 63;
    const int wid = tid >> 6;
    if (lane == 0) {
        s_red[wid][0] = t2; s_red[wid][1] = t3; s_red[wid][2] = t4;
        s_red[wid][3] = t5; s_red[wid][4] = t6; s_red[wid][5] = t7;
        s_red[wid][6] = t8;
    }
    __syncthreads();
    if (tid == 0) {
        double r[7];
        for (int q = 0; q < 7; ++q) {
            r[q] = 0.0;
            for (int w = 0; w < 4; ++w) r[q] += s_red[w][q];
        }
        const double ld = s_logs
            - r[0] / 2.0 + r[1] / 3.0 - r[2] / 4.0 + r[3] / 5.0
            - r[4] / 6.0 + r[5] / 7.0 - r[6] / 8.0;
        contrib[k] = s_w * ld;
        __threadfence();
        const unsigned old = atomicAdd(ctr, 1u);
        if (old == NCLS) {   // last of the 11 blocks
            double t = 0.0;
            for (int i = 0; i <= NCLS; ++i)
                t += atomicAdd(&contrib[i], 0.0);   // coherent read
            out[0] = (float)t;
        }
    }
}

extern "C" void kernel_launch(void* const* d_in, const int* in_sizes, int n_in,
                              void* d_out, int out_size, void* d_ws, size_t ws_size,
                              hipStream_t stream) {
    const float* embed = (const float*)d_in[0];
    const int* targets = (const int*)d_in[1];
    float* out = (float*)d_out;
    const int m = in_sizes[0] / PDIM;   // 262144

    char* ws = (char*)d_ws;
    float* gram = (float*)ws;                        // 11*4096 floats = 180224 B
    int* counts = (int*)(ws + 180224);               // 40 B
    unsigned* ctr = (unsigned*)(ws + 180264);        // 4 B
    double* contrib = (double*)(ws + 180352);        // 88 B (8-aligned)

    // zero gram accumulators + counts + done-counter
    hipMemsetAsync(ws, 0, 180268, stream);

    dim3 g1((m + CHUNK - 1) / CHUNK, NCLS);
    mcr_gram<<<g1, 256, 0, stream>>>((const float4*)embed, targets, gram, counts, m);
    mcr_logdet<<<dim3(NCLS + 1), 256, 0, stream>>>(gram, counts, contrib, ctr, out, m);
}

// Round 10
// 180.927 us; speedup vs baseline: 1.1733x; 1.1733x over previous
//
#include <hip/hip_runtime.h>
#include <math.h>

#define NCLS 10
#define SCHUNK 2048
#define BROWS 512
#define PDIM 64
#define LDX 72    // padded row length (bf16 elems) for transposed LDS tiles
#define LDE 68    // padded leading dim for 64x64 LDS matrices in logdet

typedef short bf16x8 __attribute__((ext_vector_type(8)));
typedef float f32x4 __attribute__((ext_vector_type(4)));

__device__ __forceinline__ unsigned short bf16rn(float x) {
    unsigned u = __float_as_uint(x);
    return (unsigned short)((u + 0x7FFFu + ((u >> 16) & 1u)) >> 16);
}
__device__ __forceinline__ float bf16f(unsigned short h) {
    return __uint_as_float(((unsigned)h) << 16);
}

// ---------------------------------------------------------------------------
// ws layout (memset zeroes [0, 163844) only):
//   0        float gram[10][4096]     163840
//   163840   unsigned ctr             4
//   163848   double contrib[11]       88
//   163936   int hist[10][128]        5120
//   169056   int offs[10][128]        5120
//   174176   int cls_count[10]        40
//   174216   int seg_start[11]        44
//   174260   int blk_class[522]       2088
//   176352   int sorted_idx[522*512]  1069056
// ---------------------------------------------------------------------------

// K1: per-chunk per-class histogram.
__global__ __launch_bounds__(256) void mcr_hist(
    const int* __restrict__ targets, int* __restrict__ hist, int m, int nch)
{
    __shared__ int h[NCLS];
    const int tid = threadIdx.x, c = blockIdx.x, base = c * SCHUNK;
    if (tid < NCLS) h[tid] = 0;
    __syncthreads();
    const int lim = (m - base < SCHUNK) ? (m - base) : SCHUNK;
    for (int i = tid; i < lim; i += 256) atomicAdd(&h[targets[base + i]], 1);
    __syncthreads();
    if (tid < NCLS) hist[tid * nch + c] = h[tid];
}

// K2: scan -> per-(class,chunk) scatter offsets, 512-padded class segments,
// class counts, block->class table, pad sentinels.
__global__ __launch_bounds__(256) void mcr_scan(
    const int* __restrict__ hist, int* __restrict__ offs,
    int* __restrict__ seg_start, int* __restrict__ cls_count,
    int* __restrict__ blk_class, int* __restrict__ sorted_idx,
    int nch, int nblk)
{
    __shared__ int sh[NCLS * 128];
    __shared__ int so[NCLS * 128];
    __shared__ int stot[NCLS];
    __shared__ int sseg[NCLS + 1];
    const int tid = threadIdx.x;
    for (int i = tid; i < NCLS * nch; i += 256) sh[i] = hist[i];
    __syncthreads();
    if (tid < NCLS) {
        int run = 0;
        for (int c = 0; c < nch; ++c) { so[tid * nch + c] = run; run += sh[tid * nch + c]; }
        stot[tid] = run;
    }
    __syncthreads();
    if (tid == 0) {
        int s = 0;
        for (int k = 0; k < NCLS; ++k) { sseg[k] = s; s += ((stot[k] + BROWS - 1) / BROWS) * BROWS; }
        sseg[NCLS] = s;
    }
    __syncthreads();
    for (int i = tid; i < NCLS * nch; i += 256) offs[i] = sseg[i / nch] + so[i];
    if (tid < NCLS) cls_count[tid] = stot[tid];
    if (tid < NCLS + 1) seg_start[tid] = sseg[tid];
    for (int b = tid; b < nblk; b += 256) {
        const int rs = b * BROWS;
        int k = -1;
#pragma unroll
        for (int j = 0; j < NCLS; ++j)
            if (rs >= sseg[j] && rs < sseg[j + 1]) k = j;
        blk_class[b] = k;
    }
#pragma unroll
    for (int k = 0; k < NCLS; ++k) {
        const int ps = sseg[k] + stot[k], pe = sseg[k + 1];
        for (int j = ps + tid; j < pe; j += 256) sorted_idx[j] = -1;
    }
}

// K3: scatter row indices into class-sorted order (ballot-compacted).
__global__ __launch_bounds__(256) void mcr_scatter(
    const int* __restrict__ targets, const int* __restrict__ offs,
    int* __restrict__ sorted_idx, int m, int nch)
{
    __shared__ int cur[NCLS];
    const int tid = threadIdx.x, c = blockIdx.x, base = c * SCHUNK;
    const int lane = tid & 63;
    if (tid < NCLS) cur[tid] = offs[tid * nch + c];
    __syncthreads();
    const int lim = (m - base < SCHUNK) ? (m - base) : SCHUNK;
    for (int i = tid; i < lim; i += 256) {
        const int t = targets[base + i];
#pragma unroll
        for (int k = 0; k < NCLS; ++k) {
            const unsigned long long mk = __ballot(t == k);
            if (mk) {
                int wb = 0;
                if (lane == 0) wb = atomicAdd(&cur[k], __popcll(mk));
                wb = __shfl(wb, 0);
                if (t == k) {
                    const int pre = __popcll(mk & ((1ull << lane) - 1ull));
                    sorted_idx[wb + pre] = base + i;
                }
            }
        }
    }
}

// K4: dense Gram GEMM over class-sorted rows. Each block: one class, 512 rows
// (sentinel -1 rows stage zeros), exactly 8 static 64-row steps, coop staging
// (bf16 hi/lo transposed LDS), depth-2 prefetch, 2x2 16x16 MFMA tiles/wave.
__global__ __launch_bounds__(256) void mcr_gram(
    const float4* __restrict__ embed4,
    const int* __restrict__ sorted_idx,
    const int* __restrict__ blk_class,
    float* __restrict__ gram)
{
    __shared__ unsigned short Xh[PDIM * LDX];
    __shared__ unsigned short Xl[PDIM * LDX];

    const int tid = threadIdx.x;
    const int cls = blk_class[blockIdx.x];
    if (cls < 0) return;
    const int* __restrict__ ridx = sorted_idx + blockIdx.x * BROWS;
    const int lane = tid & 63;

    const int p  = tid & 31;
    const int qA = tid >> 5;
    const int qB = qA + 8;
    const float4 z4 = make_float4(0.f, 0.f, 0.f, 0.f);

    auto load_step = [&](int s, float4& a00, float4& a01, float4& a10, float4& a11) {
        const int r0 = s * 64 + 2 * p;
        const int i0 = ridx[r0], i1 = ridx[r0 + 1];
        if (i0 >= 0) {
            a00 = embed4[(size_t)i0 * 16 + qA];
            a01 = embed4[(size_t)i0 * 16 + qB];
        } else { a00 = z4; a01 = z4; }
        if (i1 >= 0) {
            a10 = embed4[(size_t)i1 * 16 + qA];
            a11 = embed4[(size_t)i1 * 16 + qB];
        } else { a10 = z4; a11 = z4; }
    };

    auto stage_write = [&](const float4& a00, const float4& a01,
                           const float4& a10, const float4& a11) {
#pragma unroll
        for (int half = 0; half < 2; ++half) {
            const float* x0 = half ? (const float*)&a01 : (const float*)&a00;
            const float* x1 = half ? (const float*)&a11 : (const float*)&a10;
            const int qq = half ? qB : qA;
#pragma unroll
            for (int j = 0; j < 4; ++j) {
                const int f = qq * 4 + j;
                const unsigned short h0 = bf16rn(x0[j]);
                const unsigned short h1 = bf16rn(x1[j]);
                const unsigned short l0 = bf16rn(x0[j] - bf16f(h0));
                const unsigned short l1 = bf16rn(x1[j] - bf16f(h1));
                *(unsigned int*)&Xh[f * LDX + 2 * p] = (unsigned)h0 | ((unsigned)h1 << 16);
                *(unsigned int*)&Xl[f * LDX + 2 * p] = (unsigned)l0 | ((unsigned)l1 << 16);
            }
        }
    };

    const int w = tid >> 6;
    const int wr = w >> 1, wc = w & 1;
    const int fb = (lane & 15) * LDX + 8 * (lane >> 4);

    f32x4 acc[4];
#pragma unroll
    for (int i = 0; i < 4; ++i) acc[i] = (f32x4){0.f, 0.f, 0.f, 0.f};

    auto mfma_step = [&]() {
#pragma unroll
        for (int kb = 0; kb < 64; kb += 32) {
            const int t0 = (2 * wr) * 16 * LDX + fb + kb;
            const int t1 = (2 * wr + 1) * 16 * LDX + fb + kb;
            const int u0 = (2 * wc) * 16 * LDX + fb + kb;
            const int u1 = (2 * wc + 1) * 16 * LDX + fb + kb;
            const bf16x8 Ah0 = *(const bf16x8*)&Xh[t0];
            const bf16x8 Ah1 = *(const bf16x8*)&Xh[t1];
            const bf16x8 Al0 = *(const bf16x8*)&Xl[t0];
            const bf16x8 Al1 = *(const bf16x8*)&Xl[t1];
            const bf16x8 Bh0 = *(const bf16x8*)&Xh[u0];
            const bf16x8 Bh1 = *(const bf16x8*)&Xh[u1];
            const bf16x8 Bl0 = *(const bf16x8*)&Xl[u0];
            const bf16x8 Bl1 = *(const bf16x8*)&Xl[u1];

            acc[0] = __builtin_amdgcn_mfma_f32_16x16x32_bf16(Ah0, Bh0, acc[0], 0, 0, 0);
            acc[1] = __builtin_amdgcn_mfma_f32_16x16x32_bf16(Ah0, Bh1, acc[1], 0, 0, 0);
            acc[2] = __builtin_amdgcn_mfma_f32_16x16x32_bf16(Ah1, Bh0, acc[2], 0, 0, 0);
            acc[3] = __builtin_amdgcn_mfma_f32_16x16x32_bf16(Ah1, Bh1, acc[3], 0, 0, 0);

            acc[0] = __builtin_amdgcn_mfma_f32_16x16x32_bf16(Ah0, Bl0, acc[0], 0, 0, 0);
            acc[1] = __builtin_amdgcn_mfma_f32_16x16x32_bf16(Ah0, Bl1, acc[1], 0, 0, 0);
            acc[2] = __builtin_amdgcn_mfma_f32_16x16x32_bf16(Ah1, Bl0, acc[2], 0, 0, 0);
            acc[3] = __builtin_amdgcn_mfma_f32_16x16x32_bf16(Ah1, Bl1, acc[3], 0, 0, 0);

            acc[0] = __builtin_amdgcn_mfma_f32_16x16x32_bf16(Al0, Bh0, acc[0], 0, 0, 0);
            acc[1] = __builtin_amdgcn_mfma_f32_16x16x32_bf16(Al0, Bh1, acc[1], 0, 0, 0);
            acc[2] = __builtin_amdgcn_mfma_f32_16x16x32_bf16(Al1, Bh0, acc[2], 0, 0, 0);
            acc[3] = __builtin_amdgcn_mfma_f32_16x16x32_bf16(Al1, Bh1, acc[3], 0, 0, 0);
        }
    };

    float4 A00, A01, A10, A11, B00, B01, B10, B11;
    load_step(0, A00, A01, A10, A11);
    load_step(1, B00, B01, B10, B11);

#pragma unroll
    for (int s = 0; s < 8; ++s) {
        if ((s & 1) == 0) {
            stage_write(A00, A01, A10, A11);
            if (s + 2 < 8) load_step(s + 2, A00, A01, A10, A11);
        } else {
            stage_write(B00, B01, B10, B11);
            if (s + 2 < 8) load_step(s + 2, B00, B01, B10, B11);
        }
        __syncthreads();
        mfma_step();
        __syncthreads();
    }

    float* gk = gram + cls * (PDIM * PDIM);
#pragma unroll
    for (int i1 = 0; i1 < 2; ++i1)
#pragma unroll
        for (int i2 = 0; i2 < 2; ++i2) {
            const int ar = (2 * wr + i1) * 16 + (lane >> 4) * 4;
            const int b  = (2 * wc + i2) * 16 + (lane & 15);
            const f32x4 v = acc[i1 * 2 + i2];
#pragma unroll
            for (int j = 0; j < 4; ++j) {
                const int a = ar + j;
                if (a <= b) atomicAdd(&gk[a * PDIM + b], v[j]);
            }
        }
}

__device__ __forceinline__ float gU(const float* __restrict__ gram, int k, int a, int b) {
    const int lo = a < b ? a : b;
    const int hi = a < b ? b : a;
    return gram[k * (PDIM * PDIM) + lo * PDIM + hi];
}
__device__ __forceinline__ float gT(const float* __restrict__ gram, int k, int a, int b) {
    if (k < NCLS) return gU(gram, k, a, b);
    float s = 0.0f;
#pragma unroll
    for (int c = 0; c < NCLS; ++c) s += gU(gram, c, a, b);
    return s;
}

// K5: logdet via traceless-E power series (through tr E^8); last block sums.
__global__ __launch_bounds__(256) void mcr_logdet(
    const float* __restrict__ gram,
    const int* __restrict__ cls_count,
    double* __restrict__ contrib,
    unsigned* __restrict__ ctr,
    float* __restrict__ out,
    int m)
{
    __shared__ float E[PDIM * LDE];
    __shared__ float F[PDIM * LDE];
    __shared__ float H[PDIM * LDE];
    __shared__ float G3[PDIM * LDE];
    __shared__ double s_red[4][7];
    __shared__ double s_alpha, s_beta, s_logs, s_w;

    const int tid = threadIdx.x;
    const int k = blockIdx.x;
    const bool tot = (k == NCLS);

    if (tid < PDIM) {
        double d = (double)gT(gram, k, tid, tid);
#pragma unroll
        for (int off = 32; off > 0; off >>= 1) d += __shfl_down(d, off);
        if (tid == 0) {
            const double trG = d;
            const double denom = tot ? (double)m : ((double)cls_count[k] + 1e-8);
            const double c = (double)PDIM / (denom * 0.01);
            const double s = 1.0 + c * trG / (double)PDIM;
            s_alpha = c / s;
            s_beta = 1.0 / s - 1.0;
            s_logs = (double)PDIM * log(s);
            s_w = tot ? -0.5 : 0.5 * denom / (double)m;
        }
    }
    __syncthreads();

    const double alpha = s_alpha;
    const double beta = s_beta;
    const int ta = (tid >> 4) << 2;
    const int tb = (tid & 15) << 2;

#pragma unroll
    for (int i = 0; i < 4; ++i) {
        const int a = ta + i;
#pragma unroll
        for (int j = 0; j < 4; ++j) {
            const int b = tb + j;
            double v = alpha * (double)gT(gram, k, a, b);
            if (a == b) v += beta;
            E[a * LDE + b] = (float)v;
        }
    }
    __syncthreads();

    {
        float f[4][4];
#pragma unroll
        for (int i = 0; i < 4; ++i)
#pragma unroll
            for (int j = 0; j < 4; ++j) f[i][j] = 0.0f;
#pragma unroll 4
        for (int t = 0; t < PDIM; ++t) {
            const float4 ea4 = *reinterpret_cast<const float4*>(&E[t * LDE + ta]);
            const float4 eb4 = *reinterpret_cast<const float4*>(&E[t * LDE + tb]);
            const float ea[4] = {ea4.x, ea4.y, ea4.z, ea4.w};
            const float eb[4] = {eb4.x, eb4.y, eb4.z, eb4.w};
#pragma unroll
            for (int i = 0; i < 4; ++i)
#pragma unroll
                for (int j = 0; j < 4; ++j) f[i][j] = fmaf(ea[i], eb[j], f[i][j]);
        }
#pragma unroll
        for (int i = 0; i < 4; ++i)
            *reinterpret_cast<float4*>(&F[(ta + i) * LDE + tb]) =
                make_float4(f[i][0], f[i][1], f[i][2], f[i][3]);
    }
    __syncthreads();

    {
        float h[4][4], g3[4][4];
#pragma unroll
        for (int i = 0; i < 4; ++i)
#pragma unroll
            for (int j = 0; j < 4; ++j) { h[i][j] = 0.0f; g3[i][j] = 0.0f; }
#pragma unroll 4
        for (int t = 0; t < PDIM; ++t) {
            const float4 fa4 = *reinterpret_cast<const float4*>(&F[t * LDE + ta]);
            const float4 fb4 = *reinterpret_cast<const float4*>(&F[t * LDE + tb]);
            const float4 eb4 = *reinterpret_cast<const float4*>(&E[t * LDE + tb]);
            const float fa[4] = {fa4.x, fa4.y, fa4.z, fa4.w};
            const float fb[4] = {fb4.x, fb4.y, fb4.z, fb4.w};
            const float eb[4] = {eb4.x, eb4.y, eb4.z, eb4.w};
#pragma unroll
            for (int i = 0; i < 4; ++i)
#pragma unroll
                for (int j = 0; j < 4; ++j) {
                    h[i][j] = fmaf(fa[i], fb[j], h[i][j]);
                    g3[i][j] = fmaf(fa[i], eb[j], g3[i][j]);
                }
        }
#pragma unroll
        for (int i = 0; i < 4; ++i) {
            *reinterpret_cast<float4*>(&H[(ta + i) * LDE + tb]) =
                make_float4(h[i][0], h[i][1], h[i][2], h[i][3]);
            *reinterpret_cast<float4*>(&G3[(ta + i) * LDE + tb]) =
                make_float4(g3[i][0], g3[i][1], g3[i][2], g3[i][3]);
        }
    }
    __syncthreads();

    double t2 = 0, t3 = 0, t4 = 0, t5 = 0, t6 = 0, t7 = 0, t8 = 0;
#pragma unroll
    for (int i = 0; i < 4; ++i)
#pragma unroll
        for (int j = 0; j < 4; ++j) {
            const int idx = (ta + i) * LDE + tb + j;
            const double e = (double)E[idx];
            const double f = (double)F[idx];
            const double h = (double)H[idx];
            const double g = (double)G3[idx];
            t2 += e * e; t3 += f * e; t4 += f * f;
            t5 += h * e; t6 += h * f; t7 += h * g; t8 += h * h;
        }
#pragma unroll
    for (int off = 32; off > 0; off >>= 1) {
        t2 += __shfl_down(t2, off);
        t3 += __shfl_down(t3, off);
        t4 += __shfl_down(t4, off);
        t5 += __shfl_down(t5, off);
        t6 += __shfl_down(t6, off);
        t7 += __shfl_down(t7, off);
        t8 += __shfl_down(t8, off);
    }
    const int lane = tid & 63;
    const int wid = tid >> 6;
    if (lane == 0) {
        s_red[wid][0] = t2; s_red[wid][1] = t3; s_red[wid][2] = t4;
        s_red[wid][3] = t5; s_red[wid][4] = t6; s_red[wid][5] = t7;
        s_red[wid][6] = t8;
    }
    __syncthreads();
    if (tid == 0) {
        double r[7];
        for (int q = 0; q < 7; ++q) {
            r[q] = 0.0;
            for (int w = 0; w < 4; ++w) r[q] += s_red[w][q];
        }
        const double ld = s_logs
            - r[0] / 2.0 + r[1] / 3.0 - r[2] / 4.0 + r[3] / 5.0
            - r[4] / 6.0 + r[5] / 7.0 - r[6] / 8.0;
        contrib[k] = s_w * ld;
        __threadfence();
        const unsigned old = atomicAdd(ctr, 1u);
        if (old == NCLS) {
            double t = 0.0;
            for (int i = 0; i <= NCLS; ++i)
                t += atomicAdd(&contrib[i], 0.0);
            out[0] = (float)t;
        }
    }
}

extern "C" void kernel_launch(void* const* d_in, const int* in_sizes, int n_in,
                              void* d_out, int out_size, void* d_ws, size_t ws_size,
                              hipStream_t stream) {
    const float* embed = (const float*)d_in[0];
    const int* targets = (const int*)d_in[1];
    float* out = (float*)d_out;
    const int m = in_sizes[0] / PDIM;               // 262144
    const int nch = (m + SCHUNK - 1) / SCHUNK;      // 128
    const int nblk = m / BROWS + NCLS;              // 522

    char* ws = (char*)d_ws;
    float* gram      = (float*)ws;                  // 163840
    unsigned* ctr    = (unsigned*)(ws + 163840);    // 4
    double* contrib  = (double*)(ws + 163848);      // 88
    int* hist        = (int*)(ws + 163936);         // 5120
    int* offs        = (int*)(ws + 169056);         // 5120
    int* cls_count   = (int*)(ws + 174176);         // 40
    int* seg_start   = (int*)(ws + 174216);         // 44
    int* blk_class   = (int*)(ws + 174260);         // 2088
    int* sorted_idx  = (int*)(ws + 176352);         // 1069056

    hipMemsetAsync(ws, 0, 163844, stream);          // gram + ctr

    mcr_hist<<<nch, 256, 0, stream>>>(targets, hist, m, nch);
    mcr_scan<<<1, 256, 0, stream>>>(hist, offs, seg_start, cls_count,
                                    blk_class, sorted_idx, nch, nblk);
    mcr_scatter<<<nch, 256, 0, stream>>>(targets, offs, sorted_idx, m, nch);
    mcr_gram<<<nblk, 256, 0, stream>>>((const float4*)embed, sorted_idx, blk_class, gram);
    mcr_logdet<<<NCLS + 1, 256, 0, stream>>>(gram, cls_count, contrib, ctr, out, m);
}